// Round 1
// baseline (143.508 us; speedup 1.0000x reference)
//
#include <hip/hip_runtime.h>
#include <hip/hip_bf16.h>

typedef unsigned short ushort_t;
typedef __attribute__((ext_vector_type(8))) short short8;
typedef __attribute__((ext_vector_type(4))) float f32x4;

#define MFMA16(a, b, c) __builtin_amdgcn_mfma_f32_16x16x32_bf16((a), (b), (c), 0, 0, 0)

__device__ __forceinline__ unsigned short f2bf(float f) {
    union { float f; unsigned int u; } v; v.f = f;
    unsigned int u = v.u;
    return (unsigned short)((u + 0x7fffu + ((u >> 16) & 1u)) >> 16);
}

// ---------------- Projection: dst[r][c] = bf16( (src[r][:] @ W[:][c] + b[c]) * scale )
// src: [32768][128] fp32, W: [128][128] fp32 (in,out), dst bf16.
__global__ __launch_bounds__(256) void proj_kernel(
    const float* __restrict__ src, const float* __restrict__ W,
    const float* __restrict__ bias, ushort_t* __restrict__ dst, float scale)
{
    __shared__ __align__(16) ushort_t wt[128 * 128]; // W transposed [c][k], bf16, XOR-swizzled

    const int t = threadIdx.x;
    // Stage W -> LDS transposed (coalesced float4 reads of W rows)
    #pragma unroll
    for (int i = 0; i < 16; ++i) {
        int idx = t + i * 256;          // 4096 float4 chunks
        int k = idx >> 5;               // W row (input dim)
        int c0 = (idx & 31) * 4;        // W col (output dim)
        f32x4 wv = ((const f32x4*)W)[idx];
        #pragma unroll
        for (int j = 0; j < 4; ++j) {
            int c = c0 + j;
            int byte = (c * 256 + k * 2) ^ ((c & 7) << 4);
            *(ushort_t*)((char*)wt + byte) = f2bf(wv[j]);
        }
    }
    __syncthreads();

    const int w  = t >> 6;
    const int l  = t & 63;
    const int lg = l >> 4;      // lane group 0..3
    const int ln = l & 15;
    const int r0 = blockIdx.x * 64 + w * 16;
    const int acol = lg * 8;

    // A fragments: x rows -> bf16. A[row=ln][k = lg*8+e + kc*32]
    short8 afrag[4];
    #pragma unroll
    for (int kc = 0; kc < 4; ++kc) {
        const f32x4* p = (const f32x4*)(src + (size_t)(r0 + ln) * 128 + acol + kc * 32);
        f32x4 a0 = p[0], a1 = p[1];
        short8 a;
        #pragma unroll
        for (int j = 0; j < 4; ++j) { a[j] = (short)f2bf(a0[j]); a[4 + j] = (short)f2bf(a1[j]); }
        afrag[kc] = a;
    }

    #pragma unroll
    for (int ct = 0; ct < 8; ++ct) {
        f32x4 acc = {0.f, 0.f, 0.f, 0.f};
        const int c = ct * 16 + ln;
        #pragma unroll
        for (int kc = 0; kc < 4; ++kc) {
            int byte = (c * 256 + (acol + kc * 32) * 2) ^ ((c & 7) << 4);
            short8 bfr = *(const short8*)((const char*)wt + byte);
            acc = MFMA16(afrag[kc], bfr, acc);
        }
        float bv = bias[c];
        #pragma unroll
        for (int reg = 0; reg < 4; ++reg) {
            int row = r0 + lg * 4 + reg;
            dst[(size_t)row * 128 + c] = f2bf((acc[reg] + bv) * scale);
        }
    }
}

// ---------------- Flash attention: out[b][q][d] = softmax(Q Kt) V, Q pre-scaled.
// Block = 256 threads (4 waves); each wave owns 16 q-rows; block owns 64 q-rows of one batch.
#define KVBLK 64
__global__ __launch_bounds__(256) void attn_kernel(
    const ushort_t* __restrict__ Q, const ushort_t* __restrict__ K,
    const ushort_t* __restrict__ V, float* __restrict__ out)
{
    __shared__ __align__(16) ushort_t k_lds[KVBLK * 128];  // [kv][d], swizzled
    __shared__ __align__(16) ushort_t v_lds[128 * KVBLK];  // [d][kv] (transposed), swizzled
    __shared__ __align__(16) ushort_t p_lds[4 * 16 * KVBLK]; // per-wave [q16][kv64], swizzled

    const int t  = threadIdx.x;
    const int b  = blockIdx.x >> 5;          // 32 q-blocks per batch
    const int q0 = (blockIdx.x & 31) * 64;
    const ushort_t* Qb = Q + (size_t)b * 2048 * 128;
    const ushort_t* Kb = K + (size_t)b * 2048 * 128;
    const ushort_t* Vb = V + (size_t)b * 2048 * 128;

    const int w  = t >> 6;
    const int l  = t & 63;
    const int lg = l >> 4;
    const int ln = l & 15;

    // Q fragments (held in registers across the whole KV loop)
    short8 qfrag[4];
    {
        const ushort_t* qp = Qb + (size_t)(q0 + w * 16 + ln) * 128 + lg * 8;
        #pragma unroll
        for (int kc = 0; kc < 4; ++kc)
            qfrag[kc] = *(const short8*)(qp + kc * 32);
    }

    f32x4 o[8];
    #pragma unroll
    for (int dt = 0; dt < 8; ++dt) o[dt] = (f32x4){0.f, 0.f, 0.f, 0.f};
    float m[4], lsum[4];
    #pragma unroll
    for (int r = 0; r < 4; ++r) { m[r] = -__builtin_inff(); lsum[r] = 0.f; }

    for (int kt = 0; kt < 2048 / KVBLK; ++kt) {
        const int kvbase = kt * KVBLK;
        // ---- stage K tile: row-major [kv][d], 16B chunks, swizzled
        #pragma unroll
        for (int i = 0; i < 4; ++i) {
            int idx = t + i * 256;              // 1024 chunks of 8 bf16
            int row = idx >> 4;                 // kv 0..63
            int c0  = (idx & 15) * 8;           // d
            f32x4 val = *(const f32x4*)(Kb + (size_t)(kvbase + row) * 128 + c0);
            int byte = (row * 256 + c0 * 2) ^ ((row & 7) << 4);
            *(f32x4*)((char*)k_lds + byte) = val;
        }
        // ---- stage V tile transposed: [d][kv], swizzled (scalar writes)
        #pragma unroll
        for (int i = 0; i < 4; ++i) {
            int idx = t + i * 256;
            int kv = idx & 63;
            int d0 = (idx >> 6) * 8;
            f32x4 val = *(const f32x4*)(Vb + (size_t)(kvbase + kv) * 128 + d0);
            union { f32x4 v; ushort_t u[8]; } uu; uu.v = val;
            #pragma unroll
            for (int j = 0; j < 8; ++j) {
                int d = d0 + j;
                int byte = (d * 128 + kv * 2) ^ ((d & 7) << 4);
                *(ushort_t*)((char*)v_lds + byte) = uu.u[j];
            }
        }
        __syncthreads();

        // ---- QK^T: S[16q x 64kv] per wave, 4 kv-subtiles
        f32x4 s[4];
        #pragma unroll
        for (int kv16 = 0; kv16 < 4; ++kv16) {
            f32x4 acc = {0.f, 0.f, 0.f, 0.f};
            const int krow = kv16 * 16 + ln;
            #pragma unroll
            for (int kc = 0; kc < 4; ++kc) {
                int byte = (krow * 256 + (lg * 8 + kc * 32) * 2) ^ ((krow & 7) << 4);
                short8 kf = *(const short8*)((const char*)k_lds + byte);
                acc = MFMA16(qfrag[kc], kf, acc);
            }
            s[kv16] = acc;
        }

        // ---- online softmax (row r = lg*4+reg lives in the 16 lanes of group lg)
        float corr[4];
        #pragma unroll
        for (int reg = 0; reg < 4; ++reg) {
            float pm = fmaxf(fmaxf(s[0][reg], s[1][reg]), fmaxf(s[2][reg], s[3][reg]));
            pm = fmaxf(pm, __shfl_xor(pm, 1));
            pm = fmaxf(pm, __shfl_xor(pm, 2));
            pm = fmaxf(pm, __shfl_xor(pm, 4));
            pm = fmaxf(pm, __shfl_xor(pm, 8));
            float mn = fmaxf(m[reg], pm);
            corr[reg] = __expf(m[reg] - mn);
            m[reg] = mn;
            float rs = 0.f;
            #pragma unroll
            for (int t4 = 0; t4 < 4; ++t4) {
                s[t4][reg] = __expf(s[t4][reg] - mn);
                rs += s[t4][reg];
            }
            rs += __shfl_xor(rs, 1);
            rs += __shfl_xor(rs, 2);
            rs += __shfl_xor(rs, 4);
            rs += __shfl_xor(rs, 8);
            lsum[reg] = lsum[reg] * corr[reg] + rs;
        }
        #pragma unroll
        for (int dt = 0; dt < 8; ++dt) {
            #pragma unroll
            for (int reg = 0; reg < 4; ++reg) o[dt][reg] *= corr[reg];
        }

        // ---- P (D-layout) -> LDS -> A-fragments
        const unsigned wbase = w * 2048;  // bytes: 16*64*2 per wave
        #pragma unroll
        for (int kv16 = 0; kv16 < 4; ++kv16) {
            #pragma unroll
            for (int reg = 0; reg < 4; ++reg) {
                int row = lg * 4 + reg;
                int col = kv16 * 16 + ln;
                int byte = wbase + ((row * 128 + col * 2) ^ ((row & 7) << 4));
                *(ushort_t*)((char*)p_lds + byte) = f2bf(s[kv16][reg]);
            }
        }
        asm volatile("s_waitcnt lgkmcnt(0)" ::: "memory");
        short8 pfrag[2];
        #pragma unroll
        for (int ks = 0; ks < 2; ++ks) {
            int byte = wbase + ((ln * 128 + (lg * 8 + ks * 32) * 2) ^ ((ln & 7) << 4));
            pfrag[ks] = *(const short8*)((const char*)p_lds + byte);
        }

        // ---- PV: O += P @ V   (B-operand from transposed V tile)
        #pragma unroll
        for (int dt = 0; dt < 8; ++dt) {
            #pragma unroll
            for (int ks = 0; ks < 2; ++ks) {
                int d = dt * 16 + ln;
                int byte = (d * 128 + (lg * 8 + ks * 32) * 2) ^ ((d & 7) << 4);
                short8 vf = *(const short8*)((const char*)v_lds + byte);
                o[dt] = MFMA16(pfrag[ks], vf, o[dt]);
            }
        }
        __syncthreads();
    }

    // ---- epilogue: normalize and store fp32
    float* ob = out + (size_t)b * 2048 * 128;
    #pragma unroll
    for (int reg = 0; reg < 4; ++reg) {
        float inv = 1.0f / lsum[reg];
        int row = q0 + w * 16 + lg * 4 + reg;
        #pragma unroll
        for (int dt = 0; dt < 8; ++dt) {
            ob[(size_t)row * 128 + dt * 16 + ln] = o[dt][reg] * inv;
        }
    }
}

extern "C" void kernel_launch(void* const* d_in, const int* in_sizes, int n_in,
                              void* d_out, int out_size, void* d_ws, size_t ws_size,
                              hipStream_t stream) {
    (void)in_sizes; (void)n_in; (void)out_size; (void)ws_size;
    const float* x  = (const float*)d_in[0];
    const float* y  = (const float*)d_in[1];
    const float* Wq = (const float*)d_in[2];
    const float* bq = (const float*)d_in[3];
    const float* Wk = (const float*)d_in[4];
    const float* bk = (const float*)d_in[5];
    const float* Wv = (const float*)d_in[6];
    const float* bv = (const float*)d_in[7];
    float* out = (float*)d_out;

    ushort_t* qws = (ushort_t*)d_ws;
    ushort_t* kws = qws + (size_t)32768 * 128;
    ushort_t* vws = kws + (size_t)32768 * 128;

    const float inv_scale = 0.08838834764831845f; // 1/sqrt(128), folded into Q

    proj_kernel<<<512, 256, 0, stream>>>(x, Wq, bq, qws, inv_scale);
    proj_kernel<<<512, 256, 0, stream>>>(y, Wk, bk, kws, 1.0f);
    proj_kernel<<<512, 256, 0, stream>>>(y, Wv, bv, vws, 1.0f);
    attn_kernel<<<512, 256, 0, stream>>>(qws, kws, vws, out);
}

// Round 2
// 133.207 us; speedup vs baseline: 1.0773x; 1.0773x over previous
//
#include <hip/hip_runtime.h>
#include <hip/hip_bf16.h>

typedef unsigned short ushort_t;
typedef __attribute__((ext_vector_type(8))) short short8;
typedef __attribute__((ext_vector_type(4))) float f32x4;

#define MFMA16(a, b, c) __builtin_amdgcn_mfma_f32_16x16x32_bf16((a), (b), (c), 0, 0, 0)

__device__ __forceinline__ unsigned short f2bf(float f) {
    union { float f; unsigned int u; } v; v.f = f;
    unsigned int u = v.u;
    return (unsigned short)((u + 0x7fffu + ((u >> 16) & 1u)) >> 16);
}

// async global->LDS, 16B per lane. LDS dest must be wave-uniform base (+lane*16 implicit).
__device__ __forceinline__ void gl_lds16(const void* g, void* l) {
    __builtin_amdgcn_global_load_lds((const __attribute__((address_space(1))) void*)g,
                                     (__attribute__((address_space(3))) void*)l, 16, 0, 0);
}

// ---------------- Projection: dst[r][c] = bf16( (src[r][:] @ W[:][c] + b[c]) * scale )
__global__ __launch_bounds__(256) void proj_kernel(
    const float* __restrict__ src, const float* __restrict__ W,
    const float* __restrict__ bias, ushort_t* __restrict__ dst, float scale)
{
    __shared__ __align__(16) ushort_t wt[128 * 128]; // W^T [c][k], bf16, XOR-swizzled

    const int t = threadIdx.x;
    #pragma unroll
    for (int i = 0; i < 16; ++i) {
        int idx = t + i * 256;
        int k = idx >> 5;
        int c0 = (idx & 31) * 4;
        f32x4 wv = ((const f32x4*)W)[idx];
        #pragma unroll
        for (int j = 0; j < 4; ++j) {
            int c = c0 + j;
            int byte = (c * 256 + k * 2) ^ ((c & 7) << 4);
            *(ushort_t*)((char*)wt + byte) = f2bf(wv[j]);
        }
    }
    __syncthreads();

    const int w  = t >> 6;
    const int l  = t & 63;
    const int lg = l >> 4;
    const int ln = l & 15;
    const int r0 = blockIdx.x * 64 + w * 16;
    const int acol = lg * 8;

    short8 afrag[4];
    #pragma unroll
    for (int kc = 0; kc < 4; ++kc) {
        const f32x4* p = (const f32x4*)(src + (size_t)(r0 + ln) * 128 + acol + kc * 32);
        f32x4 a0 = p[0], a1 = p[1];
        short8 a;
        #pragma unroll
        for (int j = 0; j < 4; ++j) { a[j] = (short)f2bf(a0[j]); a[4 + j] = (short)f2bf(a1[j]); }
        afrag[kc] = a;
    }

    #pragma unroll
    for (int ct = 0; ct < 8; ++ct) {
        f32x4 acc = {0.f, 0.f, 0.f, 0.f};
        const int c = ct * 16 + ln;
        #pragma unroll
        for (int kc = 0; kc < 4; ++kc) {
            int byte = (c * 256 + (acol + kc * 32) * 2) ^ ((c & 7) << 4);
            short8 bfr = *(const short8*)((const char*)wt + byte);
            acc = MFMA16(afrag[kc], bfr, acc);
        }
        float bv = bias[c];
        #pragma unroll
        for (int reg = 0; reg < 4; ++reg) {
            int row = r0 + lg * 4 + reg;
            dst[(size_t)row * 128 + c] = f2bf((acc[reg] + bv) * scale);
        }
    }
}

// ---------------- V projection with transposed output: dstT[b][c][kv] = bf16(y[b][kv][:]@Wv[:][c] + bv[c])
__global__ __launch_bounds__(256) void projT_kernel(
    const float* __restrict__ src, const float* __restrict__ W,
    const float* __restrict__ bias, ushort_t* __restrict__ dstT)
{
    __shared__ __align__(16) ushort_t wt[128 * 128];
    __shared__ __align__(16) ushort_t vt[128 * 64];  // [c][row_local], swizzled

    const int t = threadIdx.x;
    #pragma unroll
    for (int i = 0; i < 16; ++i) {
        int idx = t + i * 256;
        int k = idx >> 5;
        int c0 = (idx & 31) * 4;
        f32x4 wv = ((const f32x4*)W)[idx];
        #pragma unroll
        for (int j = 0; j < 4; ++j) {
            int c = c0 + j;
            int byte = (c * 256 + k * 2) ^ ((c & 7) << 4);
            *(ushort_t*)((char*)wt + byte) = f2bf(wv[j]);
        }
    }
    __syncthreads();

    const int w  = t >> 6;
    const int l  = t & 63;
    const int lg = l >> 4;
    const int ln = l & 15;
    const int r0 = blockIdx.x * 64 + w * 16;
    const int acol = lg * 8;

    short8 afrag[4];
    #pragma unroll
    for (int kc = 0; kc < 4; ++kc) {
        const f32x4* p = (const f32x4*)(src + (size_t)(r0 + ln) * 128 + acol + kc * 32);
        f32x4 a0 = p[0], a1 = p[1];
        short8 a;
        #pragma unroll
        for (int j = 0; j < 4; ++j) { a[j] = (short)f2bf(a0[j]); a[4 + j] = (short)f2bf(a1[j]); }
        afrag[kc] = a;
    }

    #pragma unroll
    for (int ct = 0; ct < 8; ++ct) {
        f32x4 acc = {0.f, 0.f, 0.f, 0.f};
        const int c = ct * 16 + ln;
        #pragma unroll
        for (int kc = 0; kc < 4; ++kc) {
            int byte = (c * 256 + (acol + kc * 32) * 2) ^ ((c & 7) << 4);
            short8 bfr = *(const short8*)((const char*)wt + byte);
            acc = MFMA16(afrag[kc], bfr, acc);
        }
        float bv = bias[c];
        #pragma unroll
        for (int reg = 0; reg < 4; ++reg) {
            int rloc = w * 16 + lg * 4 + reg;   // 0..63
            int byte = (c * 128 + rloc * 2) ^ ((c & 7) << 4);
            *(ushort_t*)((char*)vt + byte) = f2bf(acc[reg] + bv);
        }
    }
    __syncthreads();

    // coalesced store: each thread stores 64B of one c-row
    const int r0b = blockIdx.x * 64;
    const int b   = r0b >> 11;
    const int kv0 = r0b & 2047;
    const int c    = t >> 1;
    const int half = t & 1;
    ushort_t* dst = dstT + (size_t)b * 128 * 2048 + (size_t)c * 2048 + kv0 + half * 32;
    #pragma unroll
    for (int j = 0; j < 4; ++j) {
        int byte = (c * 128 + (half * 32 + j * 8) * 2) ^ ((c & 7) << 4);
        *(short8*)(dst + j * 8) = *(const short8*)((const char*)vt + byte);
    }
}

// ---------------- Flash attention, double-buffered async staging.
#define KVBLK 64
#define NT (2048 / KVBLK)
__global__ __launch_bounds__(256) void attn_kernel(
    const ushort_t* __restrict__ Q, const ushort_t* __restrict__ K,
    const ushort_t* __restrict__ VT, float* __restrict__ out)
{
    __shared__ __align__(16) ushort_t k_lds[2][KVBLK * 128];  // [kv][d], swizzled rows of 256B
    __shared__ __align__(16) ushort_t v_lds[2][128 * KVBLK];  // [d][kv], swizzled rows of 128B
    __shared__ __align__(16) ushort_t p_lds[4 * 16 * KVBLK];  // per-wave [q16][kv64], swizzled

    const int t = threadIdx.x;
    const int bid = (int)blockIdx.x;
    const int wg = (bid & 7) * 64 + (bid >> 3);   // XCD-aware swizzle (512 % 8 == 0)
    const int b  = wg >> 5;
    const int q0 = (wg & 31) * 64;

    const char* Kb  = (const char*)(K  + (size_t)b * 2048 * 128);
    const char* VTb = (const char*)(VT + (size_t)b * 128 * 2048);
    const ushort_t* Qb = Q + (size_t)b * 2048 * 128;

    const int w  = t >> 6;
    const int l  = t & 63;
    const int lg = l >> 4;
    const int ln = l & 15;

    short8 qfrag[4];
    {
        const ushort_t* qp = Qb + (size_t)(q0 + w * 16 + ln) * 128 + lg * 8;
        #pragma unroll
        for (int kc = 0; kc < 4; ++kc)
            qfrag[kc] = *(const short8*)(qp + kc * 32);
    }

    f32x4 o[8];
    #pragma unroll
    for (int dt = 0; dt < 8; ++dt) o[dt] = (f32x4){0.f, 0.f, 0.f, 0.f};
    float m[4], lsum[4];
    #pragma unroll
    for (int r = 0; r < 4; ++r) { m[r] = -__builtin_inff(); lsum[r] = 0.f; }

    // stage tile kt into buffer buf (wave w stages 4KB of each of K,V)
    auto stage = [&](int buf, int kt) {
        const char* kb = Kb + (size_t)kt * KVBLK * 256;
        const int kv2 = kt * KVBLK * 2;
        char* kd = (char*)k_lds[buf];
        char* vd = (char*)v_lds[buf];
        #pragma unroll
        for (int i = 0; i < 4; ++i) {
            int base = w * 4096 + i * 1024;
            int p = base + l * 16;
            int spk = p ^ (((p >> 8) & 7) << 4);               // K rows 256B
            gl_lds16(kb + spk, kd + base);
            int spv = p ^ (((p >> 7) & 7) << 4);               // V^T rows 128B
            gl_lds16(VTb + (size_t)(spv >> 7) * 4096 + kv2 + (spv & 127), vd + base);
        }
    };

    stage(0, 0);
    int cur = 0;

    for (int kt = 0; kt < NT; ++kt) {
        __syncthreads();   // implicit vmcnt(0): tile kt loads landed; prev compute done
        if (kt + 1 < NT) stage(cur ^ 1, kt + 1);

        // ---- QK^T
        const char* klp = (const char*)k_lds[cur];
        f32x4 s[4];
        __builtin_amdgcn_s_setprio(1);
        #pragma unroll
        for (int kv16 = 0; kv16 < 4; ++kv16) {
            f32x4 acc = {0.f, 0.f, 0.f, 0.f};
            const int krow = kv16 * 16 + ln;
            #pragma unroll
            for (int kc = 0; kc < 4; ++kc) {
                int byte = (krow * 256 + (lg * 8 + kc * 32) * 2) ^ ((krow & 7) << 4);
                short8 kf = *(const short8*)(klp + byte);
                acc = MFMA16(qfrag[kc], kf, acc);
            }
            s[kv16] = acc;
        }
        __builtin_amdgcn_s_setprio(0);

        // ---- online softmax
        float corr[4];
        #pragma unroll
        for (int reg = 0; reg < 4; ++reg) {
            float pm = fmaxf(fmaxf(s[0][reg], s[1][reg]), fmaxf(s[2][reg], s[3][reg]));
            pm = fmaxf(pm, __shfl_xor(pm, 1));
            pm = fmaxf(pm, __shfl_xor(pm, 2));
            pm = fmaxf(pm, __shfl_xor(pm, 4));
            pm = fmaxf(pm, __shfl_xor(pm, 8));
            float mn = fmaxf(m[reg], pm);
            corr[reg] = __expf(m[reg] - mn);
            m[reg] = mn;
            float rs = 0.f;
            #pragma unroll
            for (int t4 = 0; t4 < 4; ++t4) {
                s[t4][reg] = __expf(s[t4][reg] - mn);
                rs += s[t4][reg];
            }
            rs += __shfl_xor(rs, 1);
            rs += __shfl_xor(rs, 2);
            rs += __shfl_xor(rs, 4);
            rs += __shfl_xor(rs, 8);
            lsum[reg] = lsum[reg] * corr[reg] + rs;
        }
        #pragma unroll
        for (int dt = 0; dt < 8; ++dt) {
            #pragma unroll
            for (int reg = 0; reg < 4; ++reg) o[dt][reg] *= corr[reg];
        }

        // ---- P (D-layout) -> per-wave LDS -> A-fragments
        const unsigned wbase = w * 2048;
        #pragma unroll
        for (int kv16 = 0; kv16 < 4; ++kv16) {
            #pragma unroll
            for (int reg = 0; reg < 4; ++reg) {
                int row = lg * 4 + reg;
                int col = kv16 * 16 + ln;
                int byte = wbase + ((row * 128 + col * 2) ^ ((row & 7) << 4));
                *(ushort_t*)((char*)p_lds + byte) = f2bf(s[kv16][reg]);
            }
        }
        asm volatile("s_waitcnt lgkmcnt(0)" ::: "memory");
        short8 pfrag[2];
        #pragma unroll
        for (int ks = 0; ks < 2; ++ks) {
            int byte = wbase + ((ln * 128 + (lg * 8 + ks * 32) * 2) ^ ((ln & 7) << 4));
            pfrag[ks] = *(const short8*)((const char*)p_lds + byte);
        }

        // ---- PV: O += P @ V
        const char* vlp = (const char*)v_lds[cur];
        __builtin_amdgcn_s_setprio(1);
        #pragma unroll
        for (int dt = 0; dt < 8; ++dt) {
            #pragma unroll
            for (int ks = 0; ks < 2; ++ks) {
                int d = dt * 16 + ln;
                int byte = (d * 128 + (lg * 8 + ks * 32) * 2) ^ ((d & 7) << 4);
                short8 vf = *(const short8*)(vlp + byte);
                o[dt] = MFMA16(pfrag[ks], vf, o[dt]);
            }
        }
        __builtin_amdgcn_s_setprio(0);
        cur ^= 1;
    }

    // ---- epilogue
    float* ob = out + (size_t)b * 2048 * 128;
    #pragma unroll
    for (int reg = 0; reg < 4; ++reg) {
        float inv = 1.0f / lsum[reg];
        int row = q0 + w * 16 + lg * 4 + reg;
        #pragma unroll
        for (int dt = 0; dt < 8; ++dt) {
            ob[(size_t)row * 128 + dt * 16 + ln] = o[dt][reg] * inv;
        }
    }
}

extern "C" void kernel_launch(void* const* d_in, const int* in_sizes, int n_in,
                              void* d_out, int out_size, void* d_ws, size_t ws_size,
                              hipStream_t stream) {
    (void)in_sizes; (void)n_in; (void)out_size; (void)ws_size;
    const float* x  = (const float*)d_in[0];
    const float* y  = (const float*)d_in[1];
    const float* Wq = (const float*)d_in[2];
    const float* bq = (const float*)d_in[3];
    const float* Wk = (const float*)d_in[4];
    const float* bk = (const float*)d_in[5];
    const float* Wv = (const float*)d_in[6];
    const float* bv = (const float*)d_in[7];
    float* out = (float*)d_out;

    ushort_t* qws  = (ushort_t*)d_ws;
    ushort_t* kws  = qws + (size_t)32768 * 128;
    ushort_t* vtws = kws + (size_t)32768 * 128;

    const float inv_scale = 0.08838834764831845f; // 1/sqrt(128), folded into Q

    proj_kernel<<<512, 256, 0, stream>>>(x, Wq, bq, qws, inv_scale);
    proj_kernel<<<512, 256, 0, stream>>>(y, Wk, bk, kws, 1.0f);
    projT_kernel<<<512, 256, 0, stream>>>(y, Wv, bv, vtws);
    attn_kernel<<<512, 256, 0, stream>>>(qws, kws, vtws, out);
}

// Round 3
// 120.781 us; speedup vs baseline: 1.1882x; 1.1029x over previous
//
#include <hip/hip_runtime.h>
#include <hip/hip_bf16.h>

typedef unsigned short ushort_t;
typedef __attribute__((ext_vector_type(8))) short short8;
typedef __attribute__((ext_vector_type(4))) float f32x4;
typedef __attribute__((ext_vector_type(16))) float f32x16;

#define MFMA16(a, b, c) __builtin_amdgcn_mfma_f32_16x16x32_bf16((a), (b), (c), 0, 0, 0)
#define MFMA32(a, b, c) __builtin_amdgcn_mfma_f32_32x32x16_bf16((a), (b), (c), 0, 0, 0)

__device__ __forceinline__ ushort_t f2bf(float f) {
    return __builtin_bit_cast(ushort_t, __float2bfloat16(f));
}

#define CVTPK(lo, hi) ({ unsigned int r_; \
    asm("v_cvt_pk_bf16_f32 %0, %1, %2" : "=v"(r_) : "v"(lo), "v"(hi)); r_; })

// async global->LDS, 16B per lane (LDS dest = wave-uniform base + lane*16).
__device__ __forceinline__ void gl_lds16(const void* g, void* l) {
    __builtin_amdgcn_global_load_lds((const __attribute__((address_space(1))) void*)g,
                                     (__attribute__((address_space(3))) void*)l, 16, 0, 0);
}

// ---------------- Q projection: dst[r][c] = bf16( (src[r][:] @ W[:][c] + b[c]) * scale )
__global__ __launch_bounds__(256) void proj_kernel(
    const float* __restrict__ src, const float* __restrict__ W,
    const float* __restrict__ bias, ushort_t* __restrict__ dst, float scale)
{
    __shared__ __align__(16) ushort_t wt[128 * 128]; // W^T [c][k], bf16, XOR-swizzled

    const int t = threadIdx.x;
    #pragma unroll
    for (int i = 0; i < 16; ++i) {
        int idx = t + i * 256;
        int k = idx >> 5;
        int c0 = (idx & 31) * 4;
        f32x4 wv = ((const f32x4*)W)[idx];
        #pragma unroll
        for (int j = 0; j < 4; ++j) {
            int c = c0 + j;
            int byte = (c * 256 + k * 2) ^ ((c & 7) << 4);
            *(ushort_t*)((char*)wt + byte) = f2bf(wv[j]);
        }
    }
    __syncthreads();

    const int w  = t >> 6;
    const int l  = t & 63;
    const int lg = l >> 4;
    const int ln = l & 15;
    const int r0 = blockIdx.x * 64 + w * 16;
    const int acol = lg * 8;

    short8 afrag[4];
    #pragma unroll
    for (int kc = 0; kc < 4; ++kc) {
        const f32x4* p = (const f32x4*)(src + (size_t)(r0 + ln) * 128 + acol + kc * 32);
        f32x4 a0 = p[0], a1 = p[1];
        short8 a;
        #pragma unroll
        for (int j = 0; j < 4; ++j) { a[j] = (short)f2bf(a0[j]); a[4 + j] = (short)f2bf(a1[j]); }
        afrag[kc] = a;
    }

    #pragma unroll
    for (int ct = 0; ct < 8; ++ct) {
        f32x4 acc = {0.f, 0.f, 0.f, 0.f};
        const int c = ct * 16 + ln;
        #pragma unroll
        for (int kc = 0; kc < 4; ++kc) {
            int byte = (c * 256 + (acol + kc * 32) * 2) ^ ((c & 7) << 4);
            short8 bfr = *(const short8*)((const char*)wt + byte);
            acc = MFMA16(afrag[kc], bfr, acc);
        }
        float bv = bias[c];
        #pragma unroll
        for (int reg = 0; reg < 4; ++reg) {
            int row = r0 + lg * 4 + reg;
            dst[(size_t)row * 128 + c] = f2bf((acc[reg] + bv) * scale);
        }
    }
}

// ---------------- Fused K + V^T projection (reads y once).
// K[b][kv][c] = bf16(y@Wk + bk);  VT[b][c][kv] = bf16(y@Wv + bv)
__global__ __launch_bounds__(256) void projKV_kernel(
    const float* __restrict__ src,
    const float* __restrict__ Wk, const float* __restrict__ bk,
    const float* __restrict__ Wv, const float* __restrict__ bv,
    ushort_t* __restrict__ Kd, ushort_t* __restrict__ VTd)
{
    __shared__ __align__(16) ushort_t wtk[128 * 128];
    __shared__ __align__(16) ushort_t wtv[128 * 128];
    __shared__ __align__(16) ushort_t vt[128 * 64];

    const int t = threadIdx.x;
    #pragma unroll
    for (int i = 0; i < 16; ++i) {
        int idx = t + i * 256;
        int k = idx >> 5;
        int c0 = (idx & 31) * 4;
        f32x4 wv1 = ((const f32x4*)Wk)[idx];
        f32x4 wv2 = ((const f32x4*)Wv)[idx];
        #pragma unroll
        for (int j = 0; j < 4; ++j) {
            int c = c0 + j;
            int byte = (c * 256 + k * 2) ^ ((c & 7) << 4);
            *(ushort_t*)((char*)wtk + byte) = f2bf(wv1[j]);
            *(ushort_t*)((char*)wtv + byte) = f2bf(wv2[j]);
        }
    }
    __syncthreads();

    const int w  = t >> 6;
    const int l  = t & 63;
    const int lg = l >> 4;
    const int ln = l & 15;
    const int r0 = blockIdx.x * 64 + w * 16;
    const int acol = lg * 8;

    short8 afrag[4];
    #pragma unroll
    for (int kc = 0; kc < 4; ++kc) {
        const f32x4* p = (const f32x4*)(src + (size_t)(r0 + ln) * 128 + acol + kc * 32);
        f32x4 a0 = p[0], a1 = p[1];
        short8 a;
        #pragma unroll
        for (int j = 0; j < 4; ++j) { a[j] = (short)f2bf(a0[j]); a[4 + j] = (short)f2bf(a1[j]); }
        afrag[kc] = a;
    }

    // K output (row-major)
    #pragma unroll
    for (int ct = 0; ct < 8; ++ct) {
        f32x4 acc = {0.f, 0.f, 0.f, 0.f};
        const int c = ct * 16 + ln;
        #pragma unroll
        for (int kc = 0; kc < 4; ++kc) {
            int byte = (c * 256 + (acol + kc * 32) * 2) ^ ((c & 7) << 4);
            short8 bfr = *(const short8*)((const char*)wtk + byte);
            acc = MFMA16(afrag[kc], bfr, acc);
        }
        float bvv = bk[c];
        #pragma unroll
        for (int reg = 0; reg < 4; ++reg) {
            int row = r0 + lg * 4 + reg;
            Kd[(size_t)row * 128 + c] = f2bf(acc[reg] + bvv);
        }
    }

    // V output (transposed via LDS)
    #pragma unroll
    for (int ct = 0; ct < 8; ++ct) {
        f32x4 acc = {0.f, 0.f, 0.f, 0.f};
        const int c = ct * 16 + ln;
        #pragma unroll
        for (int kc = 0; kc < 4; ++kc) {
            int byte = (c * 256 + (acol + kc * 32) * 2) ^ ((c & 7) << 4);
            short8 bfr = *(const short8*)((const char*)wtv + byte);
            acc = MFMA16(afrag[kc], bfr, acc);
        }
        float bvv = bv[c];
        #pragma unroll
        for (int reg = 0; reg < 4; ++reg) {
            int rloc = w * 16 + lg * 4 + reg;   // 0..63
            int byte = (c * 128 + rloc * 2) ^ ((c & 7) << 4);
            *(ushort_t*)((char*)vt + byte) = f2bf(acc[reg] + bvv);
        }
    }
    __syncthreads();

    const int r0b = blockIdx.x * 64;
    const int b   = r0b >> 11;
    const int kv0 = r0b & 2047;
    const int c    = t >> 1;
    const int half = t & 1;
    ushort_t* dst = VTd + (size_t)b * 128 * 2048 + (size_t)c * 2048 + kv0 + half * 32;
    #pragma unroll
    for (int j = 0; j < 4; ++j) {
        int byte = (c * 128 + (half * 32 + j * 8) * 2) ^ ((c & 7) << 4);
        *(short8*)(dst + j * 8) = *(const short8*)((const char*)vt + byte);
    }
}

// ---------------- Flash attention, swapped-QK^T 32x32 structure.
// 4 waves/block, each owns 32 q-rows; block = 128 q-rows of one batch.
#define KVBLK 64
#define NT (2048 / KVBLK)
__global__ __launch_bounds__(256) void attn_kernel(
    const ushort_t* __restrict__ Q, const ushort_t* __restrict__ K,
    const ushort_t* __restrict__ VT, float* __restrict__ out)
{
    __shared__ __align__(16) ushort_t k_lds[2][KVBLK * 128];  // [kv][d], 256B rows, swizzled
    __shared__ __align__(16) ushort_t v_lds[2][128 * KVBLK];  // [d][kv], 128B rows, swizzled

    const int t = threadIdx.x;
    const int bid = (int)blockIdx.x;
    const int wg = (bid & 7) * 32 + (bid >> 3);   // XCD swizzle, 256 blocks
    const int b    = wg >> 4;
    const int qblk = (wg & 15) * 128;

    const char* Kb  = (const char*)(K  + (size_t)b * 2048 * 128);
    const char* VTb = (const char*)(VT + (size_t)b * 128 * 2048);
    const ushort_t* Qb = Q + (size_t)b * 2048 * 128;

    const int w  = t >> 6;
    const int l  = t & 63;
    const int lq = l & 31;          // q column (QK^T) / row index (A-operands)
    const int h  = l >> 5;          // lane half
    const int swz = (l & 7) << 4;   // per-lane XOR swizzle

    // Q as B-operand fragments: lane holds Q[q0+lq][d = kc*16 + h*8 + e]
    const int q0 = qblk + w * 32;
    short8 qfrag[8];
    {
        const ushort_t* qp = Qb + (size_t)(q0 + lq) * 128 + h * 8;
        #pragma unroll
        for (int kc = 0; kc < 8; ++kc)
            qfrag[kc] = *(const short8*)(qp + kc * 16);
    }

    f32x16 o[4];
    #pragma unroll
    for (int db = 0; db < 4; ++db)
        #pragma unroll
        for (int i = 0; i < 16; ++i) o[db][i] = 0.f;
    float m = -__builtin_inff(), lsum = 0.f;

    auto stage = [&](int buf, int kt) {
        const char* kb = Kb + (size_t)kt * KVBLK * 256;
        const int kv2 = kt * KVBLK * 2;
        char* kd = (char*)k_lds[buf];
        char* vd = (char*)v_lds[buf];
        #pragma unroll
        for (int i = 0; i < 4; ++i) {
            int base = w * 4096 + i * 1024;
            int p = base + l * 16;
            int spk = p ^ (((p >> 8) & 7) << 4);               // K rows 256B
            gl_lds16(kb + spk, kd + base);
            int spv = p ^ (((p >> 7) & 7) << 4);               // V^T rows 128B
            gl_lds16(VTb + (size_t)(spv >> 7) * 4096 + kv2 + (spv & 127), vd + base);
        }
    };

    stage(0, 0);
    int cur = 0;

    for (int kt = 0; kt < NT; ++kt) {
        __syncthreads();   // staged tile kt landed (vmcnt(0) before barrier)
        if (kt + 1 < NT) stage(cur ^ 1, kt + 1);

        // ---- QK^T (swapped): S^T[kv][q] = K-tile @ Q^T
        const char* klp = (const char*)k_lds[cur];
        f32x16 s0, s1;
        #pragma unroll
        for (int i = 0; i < 16; ++i) { s0[i] = 0.f; s1[i] = 0.f; }
        __builtin_amdgcn_s_setprio(1);
        #pragma unroll
        for (int kc = 0; kc < 8; ++kc) {
            int col = (h * 16 + kc * 32) ^ swz;
            short8 kf0 = *(const short8*)(klp + lq * 256 + col);
            s0 = MFMA32(kf0, qfrag[kc], s0);
            short8 kf1 = *(const short8*)(klp + (lq + 32) * 256 + col);
            s1 = MFMA32(kf1, qfrag[kc], s1);
        }
        __builtin_amdgcn_s_setprio(0);

        // ---- online softmax, lane-local rows (log2 domain; scale folded into Q)
        float mx;
        {
            float t16[16];
            #pragma unroll
            for (int i = 0; i < 16; ++i) t16[i] = fmaxf(s0[i], s1[i]);
            #pragma unroll
            for (int i = 0; i < 8; ++i) t16[i] = fmaxf(t16[i], t16[i + 8]);
            #pragma unroll
            for (int i = 0; i < 4; ++i) t16[i] = fmaxf(t16[i], t16[i + 4]);
            mx = fmaxf(fmaxf(t16[0], t16[1]), fmaxf(t16[2], t16[3]));
        }
        mx = fmaxf(mx, __shfl_xor(mx, 32));

        if (__any(mx > m + 8.f)) {          // defer-max (T13)
            float mn = fmaxf(m, mx);
            float corr = __builtin_exp2f(m - mn);
            lsum *= corr;
            #pragma unroll
            for (int db = 0; db < 4; ++db)
                #pragma unroll
                for (int i = 0; i < 16; ++i) o[db][i] *= corr;
            m = mn;
        }
        #pragma unroll
        for (int i = 0; i < 16; ++i) {
            s0[i] = __builtin_exp2f(s0[i] - m);
            s1[i] = __builtin_exp2f(s1[i] - m);
        }
        float rs;
        {
            float a16[16];
            #pragma unroll
            for (int i = 0; i < 16; ++i) a16[i] = s0[i] + s1[i];
            #pragma unroll
            for (int i = 0; i < 8; ++i) a16[i] += a16[i + 8];
            #pragma unroll
            for (int i = 0; i < 4; ++i) a16[i] += a16[i + 4];
            rs = (a16[0] + a16[1]) + (a16[2] + a16[3]);
        }
        rs += __shfl_xor(rs, 32);
        lsum += rs;

        // ---- pack P -> bf16 B-fragments (T12, shfl-based half exchange)
        short8 pf[4];
        {
            auto pack = [&](const f32x16& sb, int a, short8& outf) {
                unsigned u0 = CVTPK(sb[a * 8 + 0], sb[a * 8 + 1]);
                unsigned u1 = CVTPK(sb[a * 8 + 2], sb[a * 8 + 3]);
                unsigned u2 = CVTPK(sb[a * 8 + 4], sb[a * 8 + 5]);
                unsigned u3 = CVTPK(sb[a * 8 + 6], sb[a * 8 + 7]);
                unsigned x0 = __shfl_xor(u0, 32);
                unsigned x1 = __shfl_xor(u1, 32);
                unsigned x2 = __shfl_xor(u2, 32);
                unsigned x3 = __shfl_xor(u3, 32);
                union { unsigned wds[4]; short8 s; } f;
                f.wds[0] = h ? x2 : u0;
                f.wds[1] = h ? x3 : u1;
                f.wds[2] = h ? u2 : x0;
                f.wds[3] = h ? u3 : x1;
                outf = f.s;
            };
            pack(s0, 0, pf[0]);
            pack(s0, 1, pf[1]);
            pack(s1, 0, pf[2]);
            pack(s1, 1, pf[3]);
        }

        // ---- PV: O^T[d][q] += V^T-tile @ P^T
        const char* vlp = (const char*)v_lds[cur];
        __builtin_amdgcn_s_setprio(1);
        #pragma unroll
        for (int db = 0; db < 4; ++db) {
            int row = db * 32 + lq;
            #pragma unroll
            for (int tt = 0; tt < 4; ++tt) {
                int byte = row * 128 + ((tt * 32 + h * 16) ^ swz);
                short8 vf = *(const short8*)(vlp + byte);
                o[db] = MFMA32(vf, pf[tt], o[db]);
            }
        }
        __builtin_amdgcn_s_setprio(0);
        cur ^= 1;
    }

    // ---- epilogue: O^T D-layout -> out[b][q][d], fp32
    float inv = 1.0f / lsum;
    float* ob = out + (size_t)b * 2048 * 128 + (size_t)(q0 + lq) * 128;
    #pragma unroll
    for (int db = 0; db < 4; ++db) {
        #pragma unroll
        for (int rq = 0; rq < 4; ++rq) {
            f32x4 st;
            #pragma unroll
            for (int j = 0; j < 4; ++j) st[j] = o[db][rq * 4 + j] * inv;
            *(f32x4*)(ob + db * 32 + rq * 8 + 4 * h) = st;
        }
    }
}

extern "C" void kernel_launch(void* const* d_in, const int* in_sizes, int n_in,
                              void* d_out, int out_size, void* d_ws, size_t ws_size,
                              hipStream_t stream) {
    (void)in_sizes; (void)n_in; (void)out_size; (void)ws_size;
    const float* x  = (const float*)d_in[0];
    const float* y  = (const float*)d_in[1];
    const float* Wq = (const float*)d_in[2];
    const float* bq = (const float*)d_in[3];
    const float* Wk = (const float*)d_in[4];
    const float* bk = (const float*)d_in[5];
    const float* Wv = (const float*)d_in[6];
    const float* bv = (const float*)d_in[7];
    float* out = (float*)d_out;

    ushort_t* qws  = (ushort_t*)d_ws;
    ushort_t* kws  = qws + (size_t)32768 * 128;
    ushort_t* vtws = kws + (size_t)32768 * 128;

    // 1/sqrt(128) * log2(e): softmax computed in exp2 domain
    const float qscale = (float)(1.4426950408889634 / 11.313708498984761);

    proj_kernel<<<512, 256, 0, stream>>>(x, Wq, bq, qws, qscale);
    projKV_kernel<<<512, 256, 0, stream>>>(y, Wk, bk, Wv, bv, kws, vtws);
    attn_kernel<<<256, 256, 0, stream>>>(qws, kws, vtws, out);
}

// Round 4
// 103.385 us; speedup vs baseline: 1.3881x; 1.1683x over previous
//
#include <hip/hip_runtime.h>
#include <hip/hip_bf16.h>

typedef unsigned short ushort_t;
typedef __attribute__((ext_vector_type(8))) short short8;
typedef __attribute__((ext_vector_type(4))) float f32x4;
typedef __attribute__((ext_vector_type(16))) float f32x16;

#define MFMA16(a, b, c) __builtin_amdgcn_mfma_f32_16x16x32_bf16((a), (b), (c), 0, 0, 0)
#define MFMA32(a, b, c) __builtin_amdgcn_mfma_f32_32x32x16_bf16((a), (b), (c), 0, 0, 0)

__device__ __forceinline__ ushort_t f2bf(float f) {
    return __builtin_bit_cast(ushort_t, __float2bfloat16(f));
}

#define CVTPK(lo, hi) ({ unsigned int r_; \
    asm("v_cvt_pk_bf16_f32 %0, %1, %2" : "=v"(r_) : "v"(lo), "v"(hi)); r_; })

__device__ __forceinline__ void gl_lds16(const void* g, void* l) {
    __builtin_amdgcn_global_load_lds((const __attribute__((address_space(1))) void*)g,
                                     (__attribute__((address_space(3))) void*)l, 16, 0, 0);
}

// ---------------- W^T precompute: WT[c][k] = bf16(W[k][c]). 24 blocks: 3 mats x 8 k-slabs.
__global__ __launch_bounds__(256) void wt_kernel(
    const float* __restrict__ Wq, const float* __restrict__ Wk, const float* __restrict__ Wv,
    ushort_t* __restrict__ WTq, ushort_t* __restrict__ WTk, ushort_t* __restrict__ WTv)
{
    __shared__ __align__(16) ushort_t wt2[128 * 24];   // [c][kloc], padded rows (48B)

    const int mat  = blockIdx.x >> 3;
    const int slab = blockIdx.x & 7;
    const float* W = (mat == 0) ? Wq : (mat == 1) ? Wk : Wv;
    ushort_t*   WT = (mat == 0) ? WTq : (mat == 1) ? WTk : WTv;

    const int t = threadIdx.x;
    #pragma unroll
    for (int i = 0; i < 2; ++i) {
        int idx = t + i * 256;                 // 512 f32x4 chunks = 16 rows x 128 c
        int kloc = idx >> 5;
        int c0   = (idx & 31) * 4;
        f32x4 v = ((const f32x4*)(W + (size_t)(slab * 16) * 128))[idx];
        #pragma unroll
        for (int j = 0; j < 4; ++j)
            wt2[(c0 + j) * 24 + kloc] = f2bf(v[j]);
    }
    __syncthreads();
    const int r    = t >> 1;
    const int half = t & 1;
    short8 v8 = *(const short8*)&wt2[r * 24 + half * 8];
    *(short8*)(WT + r * 128 + slab * 16 + half * 8) = v8;
}

// ---------------- Q projection: dst[r][c] = bf16( (src[r][:] @ W[:][c] + b[c]) * scale )
__global__ __launch_bounds__(256) void proj_kernel(
    const float* __restrict__ src, const ushort_t* __restrict__ WT,
    const float* __restrict__ bias, ushort_t* __restrict__ dst, float scale)
{
    const int t = threadIdx.x;
    const int w  = t >> 6;
    const int l  = t & 63;
    const int lg = l >> 4;
    const int ln = l & 15;
    const int r0 = blockIdx.x * 64 + w * 16;
    const int acol = lg * 8;

    short8 afrag[4];
    #pragma unroll
    for (int kc = 0; kc < 4; ++kc) {
        const f32x4* p = (const f32x4*)(src + (size_t)(r0 + ln) * 128 + acol + kc * 32);
        f32x4 a0 = p[0], a1 = p[1];
        short8 a;
        #pragma unroll
        for (int j = 0; j < 4; ++j) { a[j] = (short)f2bf(a0[j]); a[4 + j] = (short)f2bf(a1[j]); }
        afrag[kc] = a;
    }

    #pragma unroll
    for (int ct = 0; ct < 8; ++ct) {
        f32x4 acc = {0.f, 0.f, 0.f, 0.f};
        const int c = ct * 16 + ln;
        #pragma unroll
        for (int kc = 0; kc < 4; ++kc) {
            short8 bfr = *(const short8*)(WT + c * 128 + kc * 32 + acol);
            acc = MFMA16(afrag[kc], bfr, acc);
        }
        float bv = bias[c];
        #pragma unroll
        for (int reg = 0; reg < 4; ++reg) {
            int row = r0 + lg * 4 + reg;
            dst[(size_t)row * 128 + c] = f2bf((acc[reg] + bv) * scale);
        }
    }
}

// ---------------- Fused K + V^T projection.
__global__ __launch_bounds__(256) void projKV_kernel(
    const float* __restrict__ src,
    const ushort_t* __restrict__ WTk, const float* __restrict__ bk,
    const ushort_t* __restrict__ WTv, const float* __restrict__ bv,
    ushort_t* __restrict__ Kd, ushort_t* __restrict__ VTd)
{
    __shared__ __align__(16) ushort_t vt[128 * 64];

    const int t = threadIdx.x;
    const int w  = t >> 6;
    const int l  = t & 63;
    const int lg = l >> 4;
    const int ln = l & 15;
    const int r0 = blockIdx.x * 64 + w * 16;
    const int acol = lg * 8;

    short8 afrag[4];
    #pragma unroll
    for (int kc = 0; kc < 4; ++kc) {
        const f32x4* p = (const f32x4*)(src + (size_t)(r0 + ln) * 128 + acol + kc * 32);
        f32x4 a0 = p[0], a1 = p[1];
        short8 a;
        #pragma unroll
        for (int j = 0; j < 4; ++j) { a[j] = (short)f2bf(a0[j]); a[4 + j] = (short)f2bf(a1[j]); }
        afrag[kc] = a;
    }

    #pragma unroll
    for (int ct = 0; ct < 8; ++ct) {
        f32x4 acc = {0.f, 0.f, 0.f, 0.f};
        const int c = ct * 16 + ln;
        #pragma unroll
        for (int kc = 0; kc < 4; ++kc) {
            short8 bfr = *(const short8*)(WTk + c * 128 + kc * 32 + acol);
            acc = MFMA16(afrag[kc], bfr, acc);
        }
        float bvv = bk[c];
        #pragma unroll
        for (int reg = 0; reg < 4; ++reg) {
            int row = r0 + lg * 4 + reg;
            Kd[(size_t)row * 128 + c] = f2bf(acc[reg] + bvv);
        }
    }

    #pragma unroll
    for (int ct = 0; ct < 8; ++ct) {
        f32x4 acc = {0.f, 0.f, 0.f, 0.f};
        const int c = ct * 16 + ln;
        #pragma unroll
        for (int kc = 0; kc < 4; ++kc) {
            short8 bfr = *(const short8*)(WTv + c * 128 + kc * 32 + acol);
            acc = MFMA16(afrag[kc], bfr, acc);
        }
        float bvv = bv[c];
        #pragma unroll
        for (int reg = 0; reg < 4; ++reg) {
            int rloc = w * 16 + lg * 4 + reg;
            int byte = (c * 128 + rloc * 2) ^ ((c & 7) << 4);
            *(ushort_t*)((char*)vt + byte) = f2bf(acc[reg] + bvv);
        }
    }
    __syncthreads();

    const int r0b = blockIdx.x * 64;
    const int b   = r0b >> 11;
    const int kv0 = r0b & 2047;
    const int c    = t >> 1;
    const int half = t & 1;
    ushort_t* dst = VTd + (size_t)b * 128 * 2048 + (size_t)c * 2048 + kv0 + half * 32;
    #pragma unroll
    for (int j = 0; j < 4; ++j) {
        int byte = (c * 128 + (half * 32 + j * 8) * 2) ^ ((c & 7) << 4);
        *(short8*)(dst + j * 8) = *(const short8*)((const char*)vt + byte);
    }
}

// ---------------- Flash attention: 64 q/block, 4 waves = 2 q-groups x 2 kv-halves.
#define KVBLK 64
#define NT (2048 / KVBLK)
__global__ __launch_bounds__(256) void attn_kernel(
    const ushort_t* __restrict__ Q, const ushort_t* __restrict__ K,
    const ushort_t* __restrict__ VT, float* __restrict__ out)
{
    __shared__ __align__(16) char smem_[65536];
    // [0,32KB): K dbuf (2x16KB); [32KB,64KB): V dbuf (2x16KB); merge region overlays after loop.

    const int t = threadIdx.x;
    const int bid = (int)blockIdx.x;
    const int wg = (bid & 7) * 64 + (bid >> 3);   // XCD swizzle (512 % 8 == 0)
    const int b  = wg >> 5;                       // 32 blocks per batch
    const int q0blk = (wg & 31) * 64;

    const char* Kb  = (const char*)(K  + (size_t)b * 2048 * 128);
    const char* VTb = (const char*)(VT + (size_t)b * 128 * 2048);
    const ushort_t* Qb = Q + (size_t)b * 2048 * 128;

    const int w   = t >> 6;
    const int qg  = w >> 1;          // q-group 0/1
    const int kvh = w & 1;           // kv-half 0/1
    const int l  = t & 63;
    const int lq = l & 31;
    const int h  = l >> 5;
    const int swz = (l & 7) << 4;
    const int q0 = q0blk + qg * 32;

    short8 qfrag[8];
    {
        const ushort_t* qp = Qb + (size_t)(q0 + lq) * 128 + h * 8;
        #pragma unroll
        for (int kc = 0; kc < 8; ++kc)
            qfrag[kc] = *(const short8*)(qp + kc * 16);
    }

    f32x16 o[4];
    #pragma unroll
    for (int db = 0; db < 4; ++db)
        #pragma unroll
        for (int i = 0; i < 16; ++i) o[db][i] = 0.f;
    float m = -__builtin_inff(), lsum = 0.f;

    auto stage = [&](int buf, int kt) {
        const char* kb = Kb + (size_t)kt * KVBLK * 256;
        const int kv2 = kt * KVBLK * 2;
        char* kd = smem_ + buf * 16384;
        char* vd = smem_ + 32768 + buf * 16384;
        #pragma unroll
        for (int i = 0; i < 4; ++i) {
            int base = w * 4096 + i * 1024;
            int p = base + l * 16;
            int spk = p ^ (((p >> 8) & 7) << 4);
            gl_lds16(kb + spk, kd + base);
            int spv = p ^ (((p >> 7) & 7) << 4);
            gl_lds16(VTb + (size_t)(spv >> 7) * 4096 + kv2 + (spv & 127), vd + base);
        }
    };

    stage(0, 0);
    int cur = 0;

    for (int kt = 0; kt < NT; ++kt) {
        __syncthreads();
        if (kt + 1 < NT) stage(cur ^ 1, kt + 1);

        // ---- QK^T (swapped): this wave's 32-kv half only
        const char* klp = smem_ + cur * 16384;
        f32x16 s;
        #pragma unroll
        for (int i = 0; i < 16; ++i) s[i] = 0.f;
        const int krow = kvh * 32 + lq;
        __builtin_amdgcn_s_setprio(1);
        #pragma unroll
        for (int kc = 0; kc < 8; ++kc) {
            int col = (h * 16 + kc * 32) ^ swz;
            short8 kf = *(const short8*)(klp + krow * 256 + col);
            s = MFMA32(kf, qfrag[kc], s);
        }
        __builtin_amdgcn_s_setprio(0);

        // ---- online softmax over this wave's 32 kv (16 regs + partner half via shfl32)
        float mx;
        {
            float t8[8];
            #pragma unroll
            for (int i = 0; i < 8; ++i) t8[i] = fmaxf(s[i], s[i + 8]);
            #pragma unroll
            for (int i = 0; i < 4; ++i) t8[i] = fmaxf(t8[i], t8[i + 4]);
            mx = fmaxf(fmaxf(t8[0], t8[1]), fmaxf(t8[2], t8[3]));
        }
        mx = fmaxf(mx, __shfl_xor(mx, 32));

        if (__any(mx > m + 8.f)) {          // defer-max (T13)
            float mn = fmaxf(m, mx);
            float corr = __builtin_exp2f(m - mn);
            lsum *= corr;
            #pragma unroll
            for (int db = 0; db < 4; ++db)
                #pragma unroll
                for (int i = 0; i < 16; ++i) o[db][i] *= corr;
            m = mn;
        }
        #pragma unroll
        for (int i = 0; i < 16; ++i) s[i] = __builtin_exp2f(s[i] - m);
        float rs;
        {
            float a8[8];
            #pragma unroll
            for (int i = 0; i < 8; ++i) a8[i] = s[i] + s[i + 8];
            #pragma unroll
            for (int i = 0; i < 4; ++i) a8[i] += a8[i + 4];
            rs = (a8[0] + a8[1]) + (a8[2] + a8[3]);
        }
        rs += __shfl_xor(rs, 32);
        lsum += rs;

        // ---- pack P -> bf16 B-fragments (cvt_pk + half exchange)
        short8 pf[2];
        {
            auto pack = [&](int a, short8& outf) {
                unsigned u0 = CVTPK(s[a * 8 + 0], s[a * 8 + 1]);
                unsigned u1 = CVTPK(s[a * 8 + 2], s[a * 8 + 3]);
                unsigned u2 = CVTPK(s[a * 8 + 4], s[a * 8 + 5]);
                unsigned u3 = CVTPK(s[a * 8 + 6], s[a * 8 + 7]);
                unsigned x0 = __shfl_xor(u0, 32);
                unsigned x1 = __shfl_xor(u1, 32);
                unsigned x2 = __shfl_xor(u2, 32);
                unsigned x3 = __shfl_xor(u3, 32);
                union { unsigned wds[4]; short8 s8; } f;
                f.wds[0] = h ? x2 : u0;
                f.wds[1] = h ? x3 : u1;
                f.wds[2] = h ? u2 : x0;
                f.wds[3] = h ? u3 : x1;
                outf = f.s8;
            };
            pack(0, pf[0]);
            pack(1, pf[1]);
        }

        // ---- PV over this wave's kv-half
        const char* vlp = smem_ + 32768 + cur * 16384;
        __builtin_amdgcn_s_setprio(1);
        #pragma unroll
        for (int db = 0; db < 4; ++db) {
            int row = db * 32 + lq;
            #pragma unroll
            for (int ks = 0; ks < 2; ++ks) {
                int byte = row * 128 + ((kvh * 64 + ks * 32 + h * 16) ^ swz);
                short8 vf = *(const short8*)(vlp + byte);
                o[db] = MFMA32(vf, pf[ks], o[db]);
            }
        }
        __builtin_amdgcn_s_setprio(0);
        cur ^= 1;
    }

    // ---- merge kv-halves within each q-group, then store
    __syncthreads();
    float* mrg = (float*)smem_;
    const int mo = qg * 4224 + lq * 132;      // padded rows (132 floats) to spread banks
    const int mlb = 8448;

    if (kvh == 1) {
        #pragma unroll
        for (int db = 0; db < 4; ++db) {
            #pragma unroll
            for (int rq = 0; rq < 4; ++rq) {
                f32x4 v4;
                #pragma unroll
                for (int j = 0; j < 4; ++j) v4[j] = o[db][rq * 4 + j];
                *(f32x4*)&mrg[mo + db * 32 + rq * 8 + 4 * h] = v4;
            }
        }
        if (h == 0) {
            mrg[mlb + qg * 64 + lq] = m;
            mrg[mlb + 128 + qg * 64 + lq] = lsum;
        }
    }
    __syncthreads();
    if (kvh == 0) {
        float mB = mrg[mlb + qg * 64 + lq];
        float lB = mrg[mlb + 128 + qg * 64 + lq];
        float mF = fmaxf(m, mB);
        float cA = __builtin_exp2f(m - mF);
        float cB = __builtin_exp2f(mB - mF);
        float inv = 1.0f / (lsum * cA + lB * cB);
        float* ob = out + (size_t)b * 2048 * 128 + (size_t)(q0 + lq) * 128;
        #pragma unroll
        for (int db = 0; db < 4; ++db) {
            #pragma unroll
            for (int rq = 0; rq < 4; ++rq) {
                f32x4 p4 = *(const f32x4*)&mrg[mo + db * 32 + rq * 8 + 4 * h];
                f32x4 st;
                #pragma unroll
                for (int j = 0; j < 4; ++j)
                    st[j] = (o[db][rq * 4 + j] * cA + p4[j] * cB) * inv;
                *(f32x4*)(ob + db * 32 + rq * 8 + 4 * h) = st;
            }
        }
    }
}

extern "C" void kernel_launch(void* const* d_in, const int* in_sizes, int n_in,
                              void* d_out, int out_size, void* d_ws, size_t ws_size,
                              hipStream_t stream) {
    (void)in_sizes; (void)n_in; (void)out_size; (void)ws_size;
    const float* x  = (const float*)d_in[0];
    const float* y  = (const float*)d_in[1];
    const float* Wq = (const float*)d_in[2];
    const float* bq = (const float*)d_in[3];
    const float* Wk = (const float*)d_in[4];
    const float* bk = (const float*)d_in[5];
    const float* Wv = (const float*)d_in[6];
    const float* bv = (const float*)d_in[7];
    float* out = (float*)d_out;

    // W^T bf16 staged in the head of d_out (96KB); attn fully overwrites d_out afterwards.
    ushort_t* wtq = (ushort_t*)d_out;
    ushort_t* wtk = wtq + 16384;
    ushort_t* wtv = wtk + 16384;

    ushort_t* qws  = (ushort_t*)d_ws;
    ushort_t* kws  = qws + (size_t)32768 * 128;
    ushort_t* vtws = kws + (size_t)32768 * 128;

    // 1/sqrt(128) * log2(e): softmax computed in exp2 domain
    const float qscale = (float)(1.4426950408889634 / 11.313708498984761);

    wt_kernel<<<24, 256, 0, stream>>>(Wq, Wk, Wv, wtq, wtk, wtv);
    proj_kernel<<<512, 256, 0, stream>>>(x, wtq, bq, qws, qscale);
    projKV_kernel<<<512, 256, 0, stream>>>(y, wtk, bk, wtv, bv, kws, vtws);
    attn_kernel<<<512, 256, 0, stream>>>(qws, kws, vtws, out);
}